// Round 3
// baseline (5526.845 us; speedup 1.0000x reference)
//
#include <hip/hip_runtime.h>
#include <math.h>

#define BB 1024
#define CC 64
#define HH 32
#define VV 4096
#define NEL (BB*CC*HH)   // 2097152

// ---------------- device helpers ----------------

__device__ double dev_cubic(double x){
#pragma clang fp contract(off)
  const double A = -0.75;
  x = fabs(x);
  if (x <= 1.0) return ((A + 2.0)*x - (A + 3.0))*x*x + 1.0;
  if (x < 2.0)  return A*(((x - 5.0)*x + 8.0)*x - 4.0);
  return 0.0;
}

__device__ __constant__ int c_vpatch[10] = {1,2,3,4,6,9,13,18,24,32};
__device__ __constant__ int c_pref[10]   = {0,1,3,6,10,16,25,38,56,80};

// numpy scalar pairwise-8 sum of fl32 squares of 64 contiguous floats
__device__ float np_pairwise8_sq64(const float* a){
#pragma clang fp contract(off)
  float r0 = a[0]*a[0], r1 = a[1]*a[1], r2 = a[2]*a[2], r3 = a[3]*a[3];
  float r4 = a[4]*a[4], r5 = a[5]*a[5], r6 = a[6]*a[6], r7 = a[7]*a[7];
  for (int i = 8; i < 64; i += 8){
    float s0 = a[i+0]*a[i+0]; r0 = r0 + s0;
    float s1 = a[i+1]*a[i+1]; r1 = r1 + s1;
    float s2 = a[i+2]*a[i+2]; r2 = r2 + s2;
    float s3 = a[i+3]*a[i+3]; r3 = r3 + s3;
    float s4 = a[i+4]*a[i+4]; r4 = r4 + s4;
    float s5 = a[i+5]*a[i+5]; r5 = r5 + s5;
    float s6 = a[i+6]*a[i+6]; r6 = r6 + s6;
    float s7 = a[i+7]*a[i+7]; r7 = r7 + s7;
  }
  return ((r0 + r1) + (r2 + r3)) + ((r4 + r5) + (r6 + r7));
}

// setup: build resize matrices in FP32 (np.float32 M, += float(w)), zero partials
__global__ void gen_setup(float* Mdown, float* Mup, double* partial){
#pragma clang fp contract(off)
  int t = threadIdx.x;
  for (int i = t; i < 3584; i += 64) { Mdown[i] = 0.0f; Mup[i] = 0.0f; }
  if (t < 16) partial[t] = 0.0;
  __syncthreads();
  if (t < 20) {
    int si = t >> 1; int up = t & 1;
    int pn = c_vpatch[si];
    if (!up) {
      float* M = Mdown + c_pref[si]*32;          // [pn][32], align_corners=True
      for (int o = 0; o < pn; o++){
        double src = (pn == 1) ? 0.0 : (double)(o*(32-1)) / (double)(pn-1);
        double fl = floor(src); double tt = src - fl; int fli = (int)fl;
        for (int k = -1; k <= 2; k++){
          int j = fli + k; j = j < 0 ? 0 : (j > 31 ? 31 : j);
          float w = (float)dev_cubic((double)k - tt);
          M[o*32 + j] = M[o*32 + j] + w;         // fp32 accumulate like np
        }
      }
    } else {
      float* M = Mup + c_pref[si]*32;            // [32][pn], align_corners=False
      for (int o = 0; o < 32; o++){
        double src = ((double)o + 0.5) * (double)pn / 32.0 - 0.5;
        double fl = floor(src); double tt = src - fl; int fli = (int)fl;
        for (int k = -1; k <= 2; k++){
          int j = fli + k; j = j < 0 ? 0 : (j > pn-1 ? pn-1 : j);
          float w = (float)dev_cubic((double)k - tt);
          M[o*pn + j] = M[o*pn + j] + w;
        }
      }
    }
  }
}

// e32T[c][v] = emb[v][c]; e_sq[v] = numpy-pairwise8 sum of fl32 squares
__global__ void prep_emb(const float* emb, float* e32T, float* e_sq){
  int v = blockIdx.x*blockDim.x + threadIdx.x;
  if (v >= VV) return;
  float row[64];
  for (int c = 0; c < CC; c++){
    float x = emb[v*CC + c];
    row[c] = x;
    e32T[c*VV + v] = x;
  }
  e_sq[v] = np_pairwise8_sq64(row);
}

__global__ void init_f(const float* f, float* frest, float* fhat){
  for (int i = blockIdx.x*blockDim.x + threadIdx.x; i < NEL; i += gridDim.x*blockDim.x){
    frest[i] = f[i];
    fhat[i]  = 0.0f;
  }
}

__global__ void copy_f(const float* f, float* rest){
  for (int i = blockIdx.x*blockDim.x + threadIdx.x; i < NEL; i += gridDim.x*blockDim.x)
    rest[i] = f[i];
}

// rest[bc*pn+p] = sum_h M[p][h]*frest[bc*32+h], fp32 sequential, no FMA (np.einsum)
__global__ void downsample(const float* frest, float* rest, const float* M, int pn){
#pragma clang fp contract(off)
  int tid = blockIdx.x*blockDim.x + threadIdx.x;
  int total = BB*CC*pn;
  if (tid >= total) return;
  int p = tid % pn; int bc = tid / pn;
  const float* row = frest + bc*HH;
  const float* Mr = M + p*HH;
  float s = 0.0f;
  for (int h = 0; h < HH; h++){ float pr = Mr[h]*row[h]; s = s + pr; }
  rest[bc*pn + p] = s;
}

// fp32 argmin, d = fl(fl(R + e_sq_v) - 2*dot_v), ties -> lowest index (np.argmin)
__global__ __launch_bounds__(256) void argmin_k(const float* rest, const float* e32T,
                                                const float* e_sq, int* idx, int pn){
#pragma clang fp contract(off)
  __shared__ alignas(16) float rL[16][64];
  __shared__ float sR[16];
  __shared__ float sval[4][16];
  __shared__ int   sidx[4][16];
  int n0 = blockIdx.x * 16;
  int t = threadIdx.x;
  for (int e = t; e < 16*64; e += 256){
    int j = e >> 6, c = e & 63;
    int n = n0 + j; int b = n / pn, p = n % pn;
    rL[j][c] = rest[(b*CC + c)*pn + p];
  }
  __syncthreads();
  if (t < 16) sR[t] = np_pairwise8_sq64(&rL[t][0]);   // np.sum(rest*rest, axis=1)
  __syncthreads();
  float best[16]; int bidx[16];
#pragma unroll
  for (int j = 0; j < 16; j++){ best[j] = 3.0e38f; bidx[j] = 0; }
  for (int it = 0; it < 16; it++){
    int v = (it << 8) + t;
    float acc[16];
#pragma unroll
    for (int j = 0; j < 16; j++) acc[j] = 0.0f;
    for (int c = 0; c < 64; c++){
      float ec = e32T[c*VV + v];
#pragma unroll
      for (int j = 0; j < 16; j++)
        acc[j] = fmaf(ec, rL[j][c], acc[j]);     // BLAS k-ascending fp32 FMA
    }
    float es = e_sq[v];
#pragma unroll
    for (int j = 0; j < 16; j++){
      float t1 = sR[j] + es;                      // fl(R + e_sq)
      float d  = t1 - 2.0f*acc[j];                // fl(t1 - 2*dot); 2*dot exact
      if (d < best[j]) { best[j] = d; bidx[j] = v; }  // ascending v -> first-min
    }
  }
#pragma unroll
  for (int j = 0; j < 16; j++){
    float v = best[j]; int ix = bidx[j];
    for (int off = 32; off; off >>= 1){
      float ov = __shfl_down(v, off);
      int   oi = __shfl_down(ix, off);
      if (ov < v || (ov == v && oi < ix)) { v = ov; ix = oi; }
    }
    if ((t & 63) == 0) { sval[t >> 6][j] = v; sidx[t >> 6][j] = ix; }
  }
  __syncthreads();
  if (t < 16){
    float v = sval[0][t]; int ix = sidx[0][t];
    for (int w = 1; w < 4; w++){
      float ov = sval[w][t]; int oi = sidx[w][t];
      if (ov < v || (ov == v && oi < ix)) { v = ov; ix = oi; }
    }
    idx[n0 + t] = ix;
  }
}

// si<9: hu[b,c,o] = sum_p Mup[o][p]*emb[idx[b,p],c], fp32 sequential, no FMA
__global__ __launch_bounds__(256) void upsample_k(const float* e32T, const int* idx,
                                                  const float* Mup, float* hu, int pn){
#pragma clang fp contract(off)
  __shared__ int idxL[32];
  __shared__ float hL[64][24];
  __shared__ float mL[32*24];
  int b = blockIdx.x, t = threadIdx.x;
  if (t < pn) idxL[t] = idx[b*pn + t];
  for (int e = t; e < 32*pn; e += 256) mL[e] = Mup[e];
  __syncthreads();
  for (int e = t; e < 64*pn; e += 256){
    int c = e / pn, p = e % pn;
    hL[c][p] = e32T[c*VV + idxL[p]];
  }
  __syncthreads();
  for (int e = t; e < 2048; e += 256){
    int c = e >> 5, o = e & 31;
    const float* mr = mL + o*pn;
    float s = 0.0f;
    for (int p = 0; p < pn; p++){ float pr = mr[p]*hL[c][p]; s = s + pr; }
    hu[(b*64 + c)*32 + o] = s;
  }
}

// si==9: hu = gathered embeddings
__global__ void gather9(const float* e32T, const int* idx, float* hu){
  int i = blockIdx.x*blockDim.x + threadIdx.x;
  if (i >= NEL) return;
  int h = i & 31; int c = (i >> 5) & 63; int b = i >> 11;
  hu[i] = e32T[c*VV + idx[b*32 + h]];
}

// Phi (fp32 conv3 along H, im2col order: ci-major kh-minor, FMA; bias AFTER)
// + fp32 f_hat/f_rest update + levels + loss partial
__global__ __launch_bounds__(256) void phi_update(const float* hu, const float* w, const float* bias,
    const float* f, float* fhat, float* frest, float* levels_out, float* final_out,
    double* partial, int si, int is_last){
#pragma clang fp contract(off)
  __shared__ float huL[64][32];
  __shared__ double red[4];
  int b = blockIdx.x, t = threadIdx.x;
  for (int e = t; e < 2048; e += 256) huL[e >> 5][e & 31] = hu[b*2048 + e];
  __syncthreads();
  int co = t >> 2, h0 = (t & 3) * 8;
  float y[8];
#pragma unroll
  for (int u = 0; u < 8; u++) y[u] = 0.0f;
  for (int ci = 0; ci < 64; ci++){
    float x[10];
#pragma unroll
    for (int u = 0; u < 10; u++){
      int hh = h0 - 1 + u;
      x[u] = (hh < 0 || hh > 31) ? 0.0f : huL[ci][hh];
    }
    const float* wp = w + ((co*64 + ci)*3)*3 + 1;  // [co][ci][kh][kw=1]
    float w0 = wp[0], w1 = wp[3], w2 = wp[6];
#pragma unroll
    for (int u = 0; u < 8; u++){
      y[u] = fmaf(w0, x[u],   y[u]);
      y[u] = fmaf(w1, x[u+1], y[u]);
      y[u] = fmaf(w2, x[u+2], y[u]);
    }
  }
  float bb = bias[co];
  double lsum = 0.0;
  int base = b*2048 + co*32 + h0;
#pragma unroll
  for (int u = 0; u < 8; u++){
    float yv = y[u] + bb;                            // conv + bias (after)
    float hp = 0.5f*huL[co][h0+u] + 0.5f*yv;         // h*(1-r) + y*r, r=0.5
    float fh = fhat[base+u] + hp;
    fhat[base+u] = fh;
    frest[base+u] = frest[base+u] - hp;
    float fv = f[base+u];
    float dv = fh - fv;
    lsum += (double)dv*(double)dv;
    levels_out[base+u] = fh;
    if (is_last){
      float st = dv + fv;                            // fl(fl(fh-f)+f)
      final_out[base+u] = st;
    }
  }
  for (int off = 32; off; off >>= 1) lsum += __shfl_down(lsum, off);
  if ((t & 63) == 0) red[t >> 6] = lsum;
  __syncthreads();
  if (t == 0) atomicAdd(&partial[si], red[0] + red[1] + red[2] + red[3]);
}

__global__ void finalize(const double* partial, float* out_loss){
#pragma clang fp contract(off)
  float L = 0.0f;
  for (int si = 0; si < 10; si++){
    float m = (float)(partial[si] / (double)NEL);   // mean((f_hat-f)^2), fp32 value
    float t1 = 0.25f * m;
    L = L + t1;       // + BETA*mean
    L = L + m;        // + mean
  }
  L = L / 10.0f;
  *out_loss = L;
}

// ---------------- host ----------------

extern "C" void kernel_launch(void* const* d_in, const int* in_sizes, int n_in,
                              void* d_out, int out_size, void* d_ws, size_t ws_size,
                              hipStream_t stream) {
  const float* f     = (const float*)d_in[0];
  const float* emb   = (const float*)d_in[1];
  const float* phi_w = (const float*)d_in[2];
  const float* phi_b = (const float*)d_in[3];
  float* out0       = (float*)d_out;
  float* out_loss   = out0 + NEL;
  float* out_levels = out0 + NEL + 1;

  // workspace: doubles first for alignment
  double* partial = (double*)d_ws;            // 16
  float*  e32T    = (float*)(partial + 16);   // 262144
  float*  e_sq    = e32T + 262144;            // 4096
  float*  frest   = e_sq + 4096;              // NEL
  float*  fhat    = frest + NEL;              // NEL
  float*  resthu  = fhat + NEL;               // NEL (rest/hu alias, stream-ordered)
  float*  Mdown   = resthu + NEL;             // 3584
  float*  Mup     = Mdown + 3584;             // 3584
  int*    idxbuf  = (int*)(Mup + 3584);       // 32768

  // pi table: exact IEEE-fp64 mirror of np.linspace + argmin(|TICKS - si/9|)
  // -> [0,0,1,1,1,2,2,3,3,3] (si=2/si=7 near-ties resolved by fp64 rounding)
  double q = 1.0/3.0; q = q/4.0;
  double start = q;
  double stop  = 1.0 - q;
  double delta = stop - start;
  double step  = delta/3.0;
  double ticks[4];
  ticks[0] = start;
  ticks[1] = step + start;
  { double t2 = 2.0*step; ticks[2] = t2 + start; }
  ticks[3] = stop;
  int pi_tab[10];
  for (int si = 0; si < 10; si++){
    double x = (double)si / 9.0;
    int bi = 0; double bd = fabs(ticks[0] - x);
    for (int i2 = 1; i2 < 4; i2++){
      double dd = fabs(ticks[i2] - x);
      if (dd < bd) { bd = dd; bi = i2; }
    }
    pi_tab[si] = bi;
  }

  static const int vp[10]   = {1,2,3,4,6,9,13,18,24,32};
  static const int pref[10] = {0,1,3,6,10,16,25,38,56,80};

  gen_setup<<<1, 64, 0, stream>>>(Mdown, Mup, partial);
  prep_emb<<<16, 256, 0, stream>>>(emb, e32T, e_sq);
  init_f<<<2048, 256, 0, stream>>>(f, frest, fhat);

  for (int si = 0; si < 10; si++){
    int pn = vp[si];
    if (si < 9){
      int tot = BB*CC*pn;
      downsample<<<(tot + 255)/256, 256, 0, stream>>>(frest, resthu, Mdown + pref[si]*32, pn);
    } else {
      copy_f<<<2048, 256, 0, stream>>>(f, resthu);
    }
    int N = BB*pn;
    argmin_k<<<N/16, 256, 0, stream>>>(resthu, e32T, e_sq, idxbuf, pn);
    if (si < 9)
      upsample_k<<<BB, 256, 0, stream>>>(e32T, idxbuf, Mup + pref[si]*32, resthu, pn);
    else
      gather9<<<(NEL + 255)/256, 256, 0, stream>>>(e32T, idxbuf, resthu);
    phi_update<<<BB, 256, 0, stream>>>(resthu, phi_w + (size_t)pi_tab[si]*CC*CC*9,
        phi_b + (size_t)pi_tab[si]*CC, f, fhat, frest,
        out_levels + (size_t)si*NEL, out0, partial, si, si == 9 ? 1 : 0);
  }
  finalize<<<1, 1, 0, stream>>>(partial, out_loss);
}

// Round 5
// 1659.184 us; speedup vs baseline: 3.3311x; 3.3311x over previous
//
#include <hip/hip_runtime.h>
#include <math.h>

#define BB 1024
#define CC 64
#define HH 32
#define VV 4096
#define NEL (BB*CC*HH)   // 2097152

#define RT 128        // rows per argmin block
#define TV 128        // code tile in LDS
#define NSPLIT 8      // code-range splits
#define VSPL (VV/NSPLIT)   // 512
#define NTILE (VSPL/TV)    // 4

// ---------------- setup ----------------

__device__ double dev_cubic(double x){
#pragma clang fp contract(off)
  const double A = -0.75;
  x = fabs(x);
  if (x <= 1.0) return ((A + 2.0)*x - (A + 3.0))*x*x + 1.0;
  if (x < 2.0)  return A*(((x - 5.0)*x + 8.0)*x - 4.0);
  return 0.0;
}

__device__ __constant__ int c_vpatch[10] = {1,2,3,4,6,9,13,18,24,32};
__device__ __constant__ int c_pref[10]   = {0,1,3,6,10,16,25,38,56,80};

__global__ void gen_setup(float* Mdown, float* Mup, double* partial){
#pragma clang fp contract(off)
  int t = threadIdx.x;
  for (int i = t; i < 3584; i += 64) { Mdown[i] = 0.0f; Mup[i] = 0.0f; }
  if (t < 16) partial[t] = 0.0;
  __syncthreads();
  if (t < 20) {
    int si = t >> 1; int up = t & 1;
    int pn = c_vpatch[si];
    if (!up) {
      float* M = Mdown + c_pref[si]*32;          // [pn][32], align_corners=True
      for (int o = 0; o < pn; o++){
        double src = (pn == 1) ? 0.0 : (double)(o*(32-1)) / (double)(pn-1);
        double fl = floor(src); double tt = src - fl; int fli = (int)fl;
        for (int k = -1; k <= 2; k++){
          int j = fli + k; j = j < 0 ? 0 : (j > 31 ? 31 : j);
          float w = (float)dev_cubic((double)k - tt);
          M[o*32 + j] = M[o*32 + j] + w;
        }
      }
    } else {
      float* M = Mup + c_pref[si]*32;            // [32][pn], align_corners=False
      for (int o = 0; o < 32; o++){
        double src = ((double)o + 0.5) * (double)pn / 32.0 - 0.5;
        double fl = floor(src); double tt = src - fl; int fli = (int)fl;
        for (int k = -1; k <= 2; k++){
          int j = fli + k; j = j < 0 ? 0 : (j > pn-1 ? pn-1 : j);
          float w = (float)dev_cubic((double)k - tt);
          M[o*pn + j] = M[o*pn + j] + w;
        }
      }
    }
  }
}

// numpy scalar pairwise-8 sum of fl32 squares of 64 contiguous floats
__device__ float np_pairwise8_sq64(const float* a){
#pragma clang fp contract(off)
  float r0 = a[0]*a[0], r1 = a[1]*a[1], r2 = a[2]*a[2], r3 = a[3]*a[3];
  float r4 = a[4]*a[4], r5 = a[5]*a[5], r6 = a[6]*a[6], r7 = a[7]*a[7];
  for (int i = 8; i < 64; i += 8){
    float s0 = a[i+0]*a[i+0]; r0 = r0 + s0;
    float s1 = a[i+1]*a[i+1]; r1 = r1 + s1;
    float s2 = a[i+2]*a[i+2]; r2 = r2 + s2;
    float s3 = a[i+3]*a[i+3]; r3 = r3 + s3;
    float s4 = a[i+4]*a[i+4]; r4 = r4 + s4;
    float s5 = a[i+5]*a[i+5]; r5 = r5 + s5;
    float s6 = a[i+6]*a[i+6]; r6 = r6 + s6;
    float s7 = a[i+7]*a[i+7]; r7 = r7 + s7;
  }
  return ((r0 + r1) + (r2 + r3)) + ((r4 + r5) + (r6 + r7));
}

// e32T[c][v] = emb[v][c] (column-major copy for argmin staging); e_sq = pairwise8
__global__ void prep_emb(const float* emb, float* e32T, float* e_sq){
  int v = blockIdx.x*blockDim.x + threadIdx.x;
  if (v >= VV) return;
  float row[64];
  for (int c = 0; c < CC; c++){
    float x = emb[v*CC + c];
    row[c] = x;
    e32T[c*VV + v] = x;
  }
  e_sq[v] = np_pairwise8_sq64(row);
}

// init: frest=f, fhat=0, rest0 = downsample(f) at scale 0 (pn=1)
__global__ __launch_bounds__(256) void init_k(const float* __restrict__ f,
    float* frest, float* fhat, float* rest0, const float* Md0){
#pragma clang fp contract(off)
  __shared__ float frL[64][33];
  __shared__ float m0[32];
  int b = blockIdx.x, t = threadIdx.x;
  if (t < 32) m0[t] = Md0[t];
  for (int e = t; e < 2048; e += 256){
    int c = e >> 5, h = e & 31;
    float v = f[b*2048 + e];
    frL[c][h] = v;
    frest[b*2048 + e] = v;
    fhat[b*2048 + e] = 0.0f;
  }
  __syncthreads();
  if (t < 64){
    float s = 0.0f;
    for (int h = 0; h < 32; h++){ float pr = m0[h]*frL[t][h]; s = s + pr; }
    rest0[b*64 + t] = s;
  }
}

// ---------------- argmin: 128 rows x 512 codes per block, 8x8 per thread ----------------

__global__ __launch_bounds__(256) void argmin_k(const float* __restrict__ rest,
    const float* __restrict__ e32T, const float* __restrict__ e_sq,
    float* bestW, int* idxW, int pn){
#pragma clang fp contract(off)
  __shared__ float rT[64][RT];   // [c][row] 32KB
  __shared__ float eL[64][TV];   // [c][code] 32KB
  __shared__ float sR[RT];
  int n0 = blockIdx.x * RT;
  int split = blockIdx.y;
  int v0 = split * VSPL;
  int t = threadIdx.x;

  // stage rows
  for (int e = t; e < RT*64; e += 256){
    int j = e & (RT-1), c = e >> 7;
    int n = n0 + j; int b = n / pn, p = n % pn;
    rT[c][j] = rest[(b*CC + c)*pn + p];
  }
  __syncthreads();
  // row norms (np pairwise-8 order)
  if (t < RT){
#pragma clang fp contract(off)
    float r0 = rT[0][t]*rT[0][t], r1 = rT[1][t]*rT[1][t];
    float r2 = rT[2][t]*rT[2][t], r3 = rT[3][t]*rT[3][t];
    float r4 = rT[4][t]*rT[4][t], r5 = rT[5][t]*rT[5][t];
    float r6 = rT[6][t]*rT[6][t], r7 = rT[7][t]*rT[7][t];
    for (int i = 8; i < 64; i += 8){
      float s0 = rT[i+0][t]*rT[i+0][t]; r0 = r0 + s0;
      float s1 = rT[i+1][t]*rT[i+1][t]; r1 = r1 + s1;
      float s2 = rT[i+2][t]*rT[i+2][t]; r2 = r2 + s2;
      float s3 = rT[i+3][t]*rT[i+3][t]; r3 = r3 + s3;
      float s4 = rT[i+4][t]*rT[i+4][t]; r4 = r4 + s4;
      float s5 = rT[i+5][t]*rT[i+5][t]; r5 = r5 + s5;
      float s6 = rT[i+6][t]*rT[i+6][t]; r6 = r6 + s6;
      float s7 = rT[i+7][t]*rT[i+7][t]; r7 = r7 + s7;
    }
    sR[t] = ((r0 + r1) + (r2 + r3)) + ((r4 + r5) + (r6 + r7));
  }
  __syncthreads();

  int rg = t >> 4;   // 0..15, owns rows rg*8..rg*8+7
  int cg = t & 15;   // 0..15, owns codes cg*8..cg*8+7 within tile
  float sRl[8];
#pragma unroll
  for (int k2 = 0; k2 < 8; k2++) sRl[k2] = sR[rg*8 + k2];

  float best[8]; int bidx[8];
#pragma unroll
  for (int k2 = 0; k2 < 8; k2++){ best[k2] = 3.0e38f; bidx[k2] = 0; }

  for (int tile = 0; tile < NTILE; tile++){
    int vt = v0 + tile*TV;
    for (int e = t; e < (64*TV)/4; e += 256){
      int c = e >> 5;
      int v4 = e & 31;
      *(float4*)&eL[c][v4*4] = *(const float4*)&e32T[c*VV + vt + v4*4];
    }
    __syncthreads();

    float acc[8][8];
#pragma unroll
    for (int a = 0; a < 8; a++)
#pragma unroll
      for (int k = 0; k < 8; k++) acc[a][k] = 0.0f;

    for (int c = 0; c < 64; c++){
      float4 ra = *(const float4*)&rT[c][rg*8];
      float4 rb = *(const float4*)&rT[c][rg*8 + 4];
      float4 ea = *(const float4*)&eL[c][cg*8];
      float4 eb = *(const float4*)&eL[c][cg*8 + 4];
      float rr[8] = {ra.x, ra.y, ra.z, ra.w, rb.x, rb.y, rb.z, rb.w};
      float ee[8] = {ea.x, ea.y, ea.z, ea.w, eb.x, eb.y, eb.z, eb.w};
#pragma unroll
      for (int a = 0; a < 8; a++)
#pragma unroll
        for (int k = 0; k < 8; k++)
          acc[a][k] = fmaf(ee[k], rr[a], acc[a][k]);   // c-ascending, single accumulator
    }

#pragma unroll
    for (int k2 = 0; k2 < 8; k2++){
#pragma unroll
      for (int k = 0; k < 8; k++){
        float es = e_sq[vt + cg*8 + k];
        float t1 = sRl[k2] + es;                        // fl(R + e_sq)
        float d  = t1 - 2.0f*acc[k2][k];                // fl(t1 - 2*dot)
        if (d < best[k2]) { best[k2] = d; bidx[k2] = vt + cg*8 + k; }
      }
    }
    __syncthreads();
  }

#pragma unroll
  for (int k2 = 0; k2 < 8; k2++){
    float v = best[k2]; int ix = bidx[k2];
    for (int off = 8; off; off >>= 1){
      float ov = __shfl_down(v, off, 16);
      int   oi = __shfl_down(ix, off, 16);
      if (ov < v || (ov == v && oi < ix)) { v = ov; ix = oi; }
    }
    if (cg == 0){
      int n = n0 + rg*8 + k2;
      bestW[n*NSPLIT + split] = v;
      idxW [n*NSPLIT + split] = ix;
    }
  }
}

__global__ void argmin_reduce(const float* bestW, const int* idxW, int* idx, int N){
  int n = blockIdx.x*blockDim.x + threadIdx.x;
  if (n >= N) return;
  float v = bestW[n*NSPLIT]; int ix = idxW[n*NSPLIT];
  for (int s = 1; s < NSPLIT; s++){
    float ov = bestW[n*NSPLIT + s];
    if (ov < v) { v = ov; ix = idxW[n*NSPLIT + s]; }   // strict <, splits ascending: first-min
  }
  idx[n] = ix;
}

// ---------------- fused upsample/gather + Phi + next-scale downsample ----------------

__global__ __launch_bounds__(256) void fused_phi(
    const float* __restrict__ emb, const int* __restrict__ idx,
    const float* __restrict__ Mup, const float* __restrict__ w,
    const float* __restrict__ bias, const float* __restrict__ f,
    float* fhat, float* frest, float* levels_out, float* final_out,
    float* rest_next, const float* __restrict__ Mdown_next,
    double* partial, int si, int pn, int pn2, int is_last)
{
#pragma clang fp contract(off)
  __shared__ float huL[64][33];
  __shared__ union { float hE[24*64]; float frL[64*33]; } u;   // phase-disjoint
  __shared__ float wL[64*193];    // [co][ci*3+kh]
  __shared__ float mUp[32*25];    // [o][p], stride pn+1
  __shared__ float mDn[32*33];    // [p][h], stride 33
  __shared__ int idxL[32];
  __shared__ double red[4];
  int b = blockIdx.x, t = threadIdx.x;

  if (t < pn) idxL[t] = idx[b*pn + t];
  for (int e = t; e < 64*192; e += 256){
    int co = e / 192, m = e - co*192;
    wL[co*193 + m] = w[e*3 + 1];
  }
  if (pn2 > 0){
    for (int e = t; e < pn2*32; e += 256){
      int p = e >> 5, h = e & 31;
      mDn[p*33 + h] = Mdown_next[e];
    }
  }
  if (!is_last){
    for (int e = t; e < 32*pn; e += 256){
      int o = e / pn, p = e - o*pn;
      mUp[o*(pn+1) + p] = Mup[e];
    }
  }
  __syncthreads();

  if (!is_last){
    for (int e = t; e < pn*64; e += 256){
      int p = e >> 6, c = e & 63;
      u.hE[p*64 + c] = emb[idxL[p]*64 + c];
    }
    __syncthreads();
    for (int e = t; e < 2048; e += 256){
      int c = e >> 5, o = e & 31;
      const float* mr = &mUp[o*(pn+1)];
      float s = 0.0f;
      for (int p = 0; p < pn; p++){ float pr = mr[p]*u.hE[p*64 + c]; s = s + pr; }
      huL[c][o] = s;
    }
  } else {
    for (int e = t; e < 2048; e += 256){
      int h = e >> 6, c = e & 63;
      huL[c][h] = emb[idxL[h]*64 + c];
    }
  }
  __syncthreads();   // hE dead after this point

  int co = t >> 2, h0 = (t & 3) * 8;
  float y[8];
#pragma unroll
  for (int uu = 0; uu < 8; uu++) y[uu] = 0.0f;
  for (int ci = 0; ci < 64; ci++){
    float x[10];
#pragma unroll
    for (int uu = 0; uu < 10; uu++){
      int hh = h0 - 1 + uu;
      x[uu] = (hh < 0 || hh > 31) ? 0.0f : huL[ci][hh];
    }
    const float* wp = &wL[co*193 + ci*3];
    float w0 = wp[0], w1 = wp[1], w2 = wp[2];
#pragma unroll
    for (int uu = 0; uu < 8; uu++){
      y[uu] = fmaf(w0, x[uu],   y[uu]);
      y[uu] = fmaf(w1, x[uu+1], y[uu]);
      y[uu] = fmaf(w2, x[uu+2], y[uu]);
    }
  }

  float bb = bias[co];
  double lsum = 0.0;
  int base = b*2048 + co*32 + h0;
#pragma unroll
  for (int uu = 0; uu < 8; uu++){
    float yv = y[uu] + bb;
    float hp = 0.5f*huL[co][h0+uu] + 0.5f*yv;
    float fh = fhat[base+uu] + hp;
    fhat[base+uu] = fh;
    float fr = frest[base+uu] - hp;
    frest[base+uu] = fr;
    u.frL[co*33 + h0 + uu] = fr;
    float fv = f[base+uu];
    float dv = fh - fv;
    lsum += (double)dv*(double)dv;
    levels_out[base+uu] = fh;
    if (is_last) final_out[base+uu] = dv + fv;    // straight-through: fl(fl(fh-f)+f)
  }
  for (int off = 32; off; off >>= 1) lsum += __shfl_down(lsum, off);
  if ((t & 63) == 0) red[t >> 6] = lsum;
  __syncthreads();

  if (pn2 > 0){
    for (int e = t; e < 64*pn2; e += 256){
      int c = e / pn2, p = e - c*pn2;
      const float* mr = &mDn[p*33];
      float s = 0.0f;
      for (int h = 0; h < 32; h++){ float pr = mr[h]*u.frL[c*33 + h]; s = s + pr; }
      rest_next[(b*64 + c)*pn2 + p] = s;
    }
  }
  if (t == 0) atomicAdd(&partial[si], red[0] + red[1] + red[2] + red[3]);
}

__global__ void finalize(const double* partial, float* out_loss){
#pragma clang fp contract(off)
  float L = 0.0f;
  for (int si = 0; si < 10; si++){
    float m = (float)(partial[si] / (double)NEL);
    float t1 = 0.25f * m;
    L = L + t1;
    L = L + m;
  }
  L = L / 10.0f;
  *out_loss = L;
}

// ---------------- host ----------------

extern "C" void kernel_launch(void* const* d_in, const int* in_sizes, int n_in,
                              void* d_out, int out_size, void* d_ws, size_t ws_size,
                              hipStream_t stream) {
  const float* f     = (const float*)d_in[0];
  const float* emb   = (const float*)d_in[1];
  const float* phi_w = (const float*)d_in[2];
  const float* phi_b = (const float*)d_in[3];
  float* out0       = (float*)d_out;
  float* out_loss   = out0 + NEL;
  float* out_levels = out0 + NEL + 1;

  double* partial = (double*)d_ws;             // 16
  float*  e32T    = (float*)(partial + 16);    // 262144
  float*  e_sq    = e32T + 262144;             // 4096
  float*  frest   = e_sq + 4096;               // NEL
  float*  fhat    = frest + NEL;               // NEL
  float*  rest    = fhat + NEL;                // NEL (max)
  float*  Mdown   = rest + NEL;                // 3584
  float*  Mup     = Mdown + 3584;              // 3584
  float*  bestW   = Mup + 3584;                // 32768*NSPLIT
  int*    idxW    = (int*)(bestW + 32768*NSPLIT);  // 32768*NSPLIT
  int*    idxbuf  = idxW + 32768*NSPLIT;       // 32768

  // pi table: exact IEEE-fp64 mirror of np.linspace + argmin(|TICKS - si/9|)
  double q = 1.0/3.0; q = q/4.0;
  double start = q;
  double stop  = 1.0 - q;
  double delta = stop - start;
  double step  = delta/3.0;
  double ticks[4];
  ticks[0] = start;
  ticks[1] = step + start;
  { double t2 = 2.0*step; ticks[2] = t2 + start; }
  ticks[3] = stop;
  int pi_tab[10];
  for (int si = 0; si < 10; si++){
    double x = (double)si / 9.0;
    int bi = 0; double bd = fabs(ticks[0] - x);
    for (int i2 = 1; i2 < 4; i2++){
      double dd = fabs(ticks[i2] - x);
      if (dd < bd) { bd = dd; bi = i2; }
    }
    pi_tab[si] = bi;
  }

  static const int vp[10]   = {1,2,3,4,6,9,13,18,24,32};
  static const int pref[10] = {0,1,3,6,10,16,25,38,56,80};

  gen_setup<<<1, 64, 0, stream>>>(Mdown, Mup, partial);
  prep_emb<<<16, 256, 0, stream>>>(emb, e32T, e_sq);
  init_k<<<BB, 256, 0, stream>>>(f, frest, fhat, rest, Mdown /* scale0: [1][32] */);

  for (int si = 0; si < 10; si++){
    int pn = vp[si];
    int N = BB*pn;
    dim3 ag(N/RT, NSPLIT);
    // LAST SCALE quantizes f itself (reference: rest = f). f's [b,c,h] layout
    // coincides with rest layout at pn=32, so pass f directly — no copy.
    const float* restp = (si == 9) ? f : rest;
    argmin_k<<<ag, 256, 0, stream>>>(restp, e32T, e_sq, bestW, idxW, pn);
    argmin_reduce<<<(N + 255)/256, 256, 0, stream>>>(bestW, idxW, idxbuf, N);
    // next-scale downsample only needed for si+1 <= 8 (scale 9 uses f, not rest)
    int pn2 = (si < 8) ? vp[si+1] : 0;
    fused_phi<<<BB, 256, 0, stream>>>(emb, idxbuf, Mup + pref[si]*32,
        phi_w + (size_t)pi_tab[si]*CC*CC*9, phi_b + (size_t)pi_tab[si]*CC,
        f, fhat, frest, out_levels + (size_t)si*NEL, out0,
        rest, (si < 8) ? (Mdown + pref[si+1]*32) : Mdown,
        partial, si, pn, pn2, si == 9 ? 1 : 0);
  }
  finalize<<<1, 1, 0, stream>>>(partial, out_loss);
}